// Round 13
// baseline (105.930 us; speedup 1.0000x reference)
//
#include <hip/hip_runtime.h>
#include <math.h>

// LeNet-ish forward, fp32, B=8192.
// conv1+pool = stride-2 6x6 conv (w6 = W1 (*) ones(2,2), /4 at use).
// conv1 -> S1 (2x2 window-sum of sigmoid output) in LDS -> conv2 (S-trick)
// in the same kernel. h2 contiguous [B][320].
// r11: k_fc rebuilt GEMM-style. r2..r10 evidence: every global-weight-stream
// variant is latency-bound (VALUBusy 10-17%, dur ~ #weight-passes x L2 lat).
// Weights now staged in LDS (FC1 K-tiled dbuf, FC2 whole) -> inner loop is
// ds_read_b128 + broadcast + FMA.
//
// ws: [w6 4KB][w2q 32KB][h2: B*320 f32]

__device__ __forceinline__ float sigf(float v) {
    return 1.0f / (1.0f + __expf(-v));
}

// --- K0: prep. w6[ky][c][8] from W1; w2q repack. ---
__global__ void k_prep(const float* __restrict__ W1, const float* __restrict__ W2,
                       float* __restrict__ w6, float* __restrict__ w2q) {
    int i = blockIdx.x * 256 + threadIdx.x;
    if (i < 5000) {
        int kx = i % 5, t = i / 5;
        int ky = t % 5, t2 = t / 5;
        int ic = t2 % 10, c = t2 / 10;
        w2q[((ic * 5 + ky) * 20 + c) * 5 + kx] = W2[i];
    }
    int k = i - 5000;
    if (k >= 0 && k < 480) {
        int kx = k % 8, t = k / 8;
        int c = t % 10, ky = t / 10;
        float v = 0.f;
        if (kx < 6) {
            for (int dy = 0; dy < 2; ++dy)
                for (int dx = 0; dx < 2; ++dx) {
                    int sy = ky - dy, sx = kx - dx;
                    if (sy >= 0 && sy < 5 && sx >= 0 && sx < 5)
                        v += W1[c * 25 + sy * 5 + sx];
                }
        }
        w6[k] = v;
    }
}

// --- K1: fused convs (unchanged from r9, passed). 512 thr, 8 img/block. ---
#define S1STR 1348

__global__ __launch_bounds__(512) void k_convs(
    const float* __restrict__ x, const float* __restrict__ w6g,
    const float* __restrict__ b1, const float* __restrict__ w2qg,
    const float* __restrict__ b2, float* __restrict__ h2) {
    __shared__ float S1t[8 * S1STR];
    __shared__ float XW[6272];
    __shared__ float wq1[480];
    __shared__ float bs1[10];
    __shared__ float bs2[20];

    const int tid = threadIdx.x;
    const long img0 = (long)blockIdx.x * 8;

    {
        const float4* xg = (const float4*)(x + img0 * 784);
        float4* xl = (float4*)XW;
        for (int i = tid; i < 1568; i += 512) xl[i] = xg[i];
    }
    if (tid < 480) wq1[tid] = w6g[tid];
    else if (tid < 490) bs1[tid - 480] = b1[tid - 480];
    else if (tid < 510) bs2[tid - 490] = b2[tid - 490];
    __syncthreads();

    {
        const int im = tid >> 6, l = tid & 63;
        if (l < 60) {
            const int cc = l / 12, py = l % 12, ch0 = cc * 2;
            float acc0[12], acc1[12];
#pragma unroll
            for (int p = 0; p < 12; ++p) { acc0[p] = 0.f; acc1[p] = 0.f; }

            const float* xim = XW + im * 784;
#pragma unroll
            for (int ky = 0; ky < 6; ++ky) {
                const int r = 2 * py + ky;
                union { float4 v[7]; float f[28]; } R;
                const float4* rp = (const float4*)(xim + r * 28);
#pragma unroll
                for (int q = 0; q < 7; ++q) R.v[q] = rp[q];
                union { float4 v[2]; float f[8]; } W0, W1;
                const float* wb = &wq1[(ky * 10 + ch0) * 8];
                W0.v[0] = *(const float4*)(wb);
                W0.v[1] = *(const float4*)(wb + 4);
                W1.v[0] = *(const float4*)(wb + 8);
                W1.v[1] = *(const float4*)(wb + 12);
#pragma unroll
                for (int kx = 0; kx < 6; ++kx) {
                    const float w0 = W0.f[kx], w1 = W1.f[kx];
#pragma unroll
                    for (int px = 0; px < 12; ++px) {
                        const float xv = R.f[2 * px + kx];
                        acc0[px] += xv * w0;
                        acc1[px] += xv * w1;
                    }
                }
            }

#define FINISH_CH(ACC, CH)                                                   \
            {                                                                \
                float h[12];                                                 \
                _Pragma("unroll")                                            \
                for (int px = 0; px < 12; ++px)                              \
                    h[px] = sigf(ACC[px] * 0.25f + bs1[CH]);                 \
                float hh[11];                                                \
                _Pragma("unroll")                                            \
                for (int t = 0; t < 11; ++t) hh[t] = h[t] + h[t + 1];        \
                float o[12];                                                 \
                _Pragma("unroll")                                            \
                for (int t = 0; t < 11; ++t)                                 \
                    o[t] = hh[t] + __shfl_down(hh[t], 1, 64);                \
                o[11] = 0.f;                                                 \
                if (py < 11) {                                               \
                    float* sp = S1t + im * S1STR + (CH) * 132 + py * 12;     \
                    ((float4*)sp)[0] = make_float4(o[0], o[1], o[2], o[3]);  \
                    ((float4*)sp)[1] = make_float4(o[4], o[5], o[6], o[7]);  \
                    ((float4*)sp)[2] = make_float4(o[8], o[9], o[10], o[11]);\
                }                                                            \
            }
            FINISH_CH(acc0, ch0)
            FINISH_CH(acc1, ch0 + 1)
#undef FINISH_CH
        }
    }
    __syncthreads();

    for (int i = tid; i < 5000; i += 512) XW[i] = w2qg[i];
    __syncthreads();

    if (tid < 320) {
        const int im = tid / 40, r = tid % 40;
        const int cg = r / 8, py = (r >> 1) & 3, xh = r & 1;

        float acc[4][2];
#pragma unroll
        for (int a = 0; a < 4; ++a) { acc[a][0] = 0.f; acc[a][1] = 0.f; }

        const float* s1 = S1t + im * S1STR;
        for (int ic = 0; ic < 10; ++ic) {
#pragma unroll
            for (int ky = 0; ky < 5; ++ky) {
                const int ro = ic * 132 + (2 * py + ky) * 12 + xh * 4;
                union { float4 v[2]; float f[8]; } R;
                R.v[0] = *(const float4*)(s1 + ro);
                R.v[1] = *(const float4*)(s1 + ro + 4);
                union { float4 v[5]; float f[20]; } W;
                const float4* wp = (const float4*)(XW + (ic * 5 + ky) * 100 + cg * 20);
#pragma unroll
                for (int q = 0; q < 5; ++q) W.v[q] = wp[q];
#pragma unroll
                for (int cc = 0; cc < 4; ++cc)
#pragma unroll
                    for (int kx = 0; kx < 5; ++kx) {
                        const float wv = W.f[cc * 5 + kx];
                        acc[cc][0] += R.f[kx] * wv;
                        acc[cc][1] += R.f[2 + kx] * wv;
                    }
            }
        }

        float* outp = h2 + (img0 + im) * 320 + (cg * 4) * 16 + py * 4 + xh * 2;
#pragma unroll
        for (int cc = 0; cc < 4; ++cc) {
            const float bv = bs2[cg * 4 + cc];
            float2 o;
            o.x = sigf(acc[cc][0] * 0.25f + bv);
            o.y = sigf(acc[cc][1] * 0.25f + bv);
            *(float2*)(outp + cc * 16) = o;
        }
    }
}

// --- K2: FC chain, GEMM-style with LDS-resident weights. ---
// 16 img/block, grid 512, 256 threads, 72KB LDS -> 2 blk/CU = 16 waves/CU.
// FC1: W dbuf [2][32][128] K-tiles, T14 async stage; thread=(img-pair,out-quad):
//   per k = 1 ds_read_b128 (contiguous, conflict-free) + broadcast f2 + 8 FMA.
// FC2: whole 120x84 W staged into dead h2t/wt region. FC3 from LDS.
#define TSTR 18
__global__ __launch_bounds__(256) void k_fc(
    const float* __restrict__ h2, const float* __restrict__ L1,
    const float* __restrict__ Lb1, const float* __restrict__ L2,
    const float* __restrict__ Lb2, const float* __restrict__ L3,
    const float* __restrict__ Lb3, float* __restrict__ out) {
    __shared__ float arena[18480];   // 73920 B
    float* h2t = arena;              // [320][18]  = 5760   (FC1)
    float* wt  = arena + 5760;       // [2][32][128] = 8192 (FC1)
    float* g1t = arena + 13952;      // [120][18] = 2160
    float* g2t = arena + 16112;      // [84][18]  = 1512
    float* L3s = arena + 17624;      // 840 + 10
    // FC2 phase: w2 = arena[0..10560) [120][88] (overlaps h2t+wt, both dead)

    const int tid = threadIdx.x;
    const long img0 = (long)blockIdx.x * 16;

    // stage h2t transposed (coalesced f4 reads)
    for (int i = tid; i < 1280; i += 256) {
        const int im = i / 80, fq = i % 80;
        float4 v = *(const float4*)(h2 + (img0 + im) * 320 + fq * 4);
        h2t[(fq * 4 + 0) * TSTR + im] = v.x;
        h2t[(fq * 4 + 1) * TSTR + im] = v.y;
        h2t[(fq * 4 + 2) * TSTR + im] = v.z;
        h2t[(fq * 4 + 3) * TSTR + im] = v.w;
    }
    // stage FC1 W tile 0
#pragma unroll
    for (int r = 0; r < 4; ++r) {
        const int idx = tid + 256 * r, row = idx >> 5, c4 = idx & 31;
        if (c4 < 30)
            *(float4*)(wt + row * 128 + c4 * 4) =
                *(const float4*)(L1 + row * 120 + c4 * 4);
    }
    __syncthreads();

    const int p = tid >> 5, jg = tid & 31;
    const int jc = jg < 30 ? jg : 29;

    // ---- FC1: 320 -> 120, 10 K-tiles of 32, double-buffered ----
    float acc[4][2];
    {
        union { float4 v; float f[4]; } bv;
        bv.v = *(const float4*)(Lb1 + jc * 4);
#pragma unroll
        for (int q = 0; q < 4; ++q) { acc[q][0] = bv.f[q]; acc[q][1] = bv.f[q]; }
    }
    int cur = 0;
    for (int t = 0; t < 10; ++t) {
        float4 wr0, wr1, wr2, wr3;
        if (t < 9) {  // T14: issue next-tile loads before compute
            const int k0n = (t + 1) * 32;
            const int r0 = tid >> 5, c0 = tid & 31;
            wr0 = (c0 < 30) ? *(const float4*)(L1 + (k0n + r0) * 120 + c0 * 4) : make_float4(0, 0, 0, 0);
            const int r1 = (tid + 256) >> 5, c1 = tid & 31;
            wr1 = (c1 < 30) ? *(const float4*)(L1 + (k0n + r1) * 120 + c1 * 4) : make_float4(0, 0, 0, 0);
            const int r2 = (tid + 512) >> 5;
            wr2 = (c0 < 30) ? *(const float4*)(L1 + (k0n + r2) * 120 + c0 * 4) : make_float4(0, 0, 0, 0);
            const int r3 = (tid + 768) >> 5;
            wr3 = (c0 < 30) ? *(const float4*)(L1 + (k0n + r3) * 120 + c0 * 4) : make_float4(0, 0, 0, 0);
        }
        const float* wb = wt + cur * 4096;
        const int kb = t * 32;
#pragma unroll
        for (int k = 0; k < 32; ++k) {
            union { float4 v; float f[4]; } w;
            w.v = *(const float4*)(wb + k * 128 + jc * 4);
            const float2 h = *(const float2*)&h2t[(kb + k) * TSTR + p * 2];
#pragma unroll
            for (int q = 0; q < 4; ++q) {
                acc[q][0] += w.f[q] * h.x;
                acc[q][1] += w.f[q] * h.y;
            }
        }
        if (t < 9) {  // write prefetched tile, flip buffers
            float* wd = wt + (cur ^ 1) * 4096;
            const int c0 = tid & 31;
            if (c0 < 30) {
                *(float4*)(wd + (tid >> 5) * 128 + c0 * 4) = wr0;
                *(float4*)(wd + ((tid + 256) >> 5) * 128 + c0 * 4) = wr1;
                *(float4*)(wd + ((tid + 512) >> 5) * 128 + c0 * 4) = wr2;
                *(float4*)(wd + ((tid + 768) >> 5) * 128 + c0 * 4) = wr3;
            }
            cur ^= 1;
        }
        __syncthreads();
    }
    if (jg < 30) {
#pragma unroll
        for (int q = 0; q < 4; ++q) {
            g1t[(jg * 4 + q) * TSTR + p * 2 + 0] = sigf(acc[q][0]);
            g1t[(jg * 4 + q) * TSTR + p * 2 + 1] = sigf(acc[q][1]);
        }
    }
    __syncthreads();

    // ---- stage FC2 weights [120][88] (raw L2 [120][84]) + L3/Lb3 ----
    for (int i = tid; i < 2520; i += 256) {
        const int row = i / 21, c4 = i % 21;
        *(float4*)(arena + row * 88 + c4 * 4) =
            *(const float4*)(L2 + row * 84 + c4 * 4);
    }
    for (int i = tid; i < 840; i += 256) L3s[i] = L3[i];
    if (tid < 10) L3s[840 + tid] = Lb3[tid];
    __syncthreads();

    // ---- FC2: 120 -> 84 ----
    if (jg < 21) {
        union { float4 v; float f[4]; } bv;
        bv.v = *(const float4*)(Lb2 + jg * 4);
        float a2[4][2];
#pragma unroll
        for (int q = 0; q < 4; ++q) { a2[q][0] = bv.f[q]; a2[q][1] = bv.f[q]; }
#pragma unroll 4
        for (int k = 0; k < 120; ++k) {
            union { float4 v; float f[4]; } w;
            w.v = *(const float4*)(arena + k * 88 + jg * 4);
            const float2 h = *(const float2*)&g1t[k * TSTR + p * 2];
#pragma unroll
            for (int q = 0; q < 4; ++q) {
                a2[q][0] += w.f[q] * h.x;
                a2[q][1] += w.f[q] * h.y;
            }
        }
#pragma unroll
        for (int q = 0; q < 4; ++q) {
            g2t[(jg * 4 + q) * TSTR + p * 2 + 0] = sigf(a2[q][0]);
            g2t[(jg * 4 + q) * TSTR + p * 2 + 1] = sigf(a2[q][1]);
        }
    }
    __syncthreads();

    // ---- FC3: 84 -> 10 ----
    if (tid < 160) {
        const int im = tid / 10, j = tid % 10;
        float a = L3s[840 + j];
#pragma unroll 4
        for (int i = 0; i < 84; ++i)
            a += g2t[i * TSTR + im] * L3s[i * 10 + j];
        out[(img0 + im) * 10 + j] = a;
    }
}

extern "C" void kernel_launch(void* const* d_in, const int* in_sizes, int n_in,
                              void* d_out, int out_size, void* d_ws, size_t ws_size,
                              hipStream_t stream) {
    const float* x   = (const float*)d_in[0];
    const float* W1  = (const float*)d_in[1];
    const float* b1  = (const float*)d_in[2];
    const float* W2  = (const float*)d_in[3];
    const float* b2  = (const float*)d_in[4];
    const float* L1  = (const float*)d_in[5];
    const float* Lb1 = (const float*)d_in[6];
    const float* L2  = (const float*)d_in[7];
    const float* Lb2 = (const float*)d_in[8];
    const float* L3  = (const float*)d_in[9];
    const float* Lb3 = (const float*)d_in[10];
    float* out = (float*)d_out;

    const int B = in_sizes[0] / 784;  // 8192

    char* ws = (char*)d_ws;
    float* w6  = (float*)ws;                 // 1.9KB (pad 4KB)
    float* w2q = (float*)(ws + 4096);        // 20KB (pad 32KB)
    float* h2  = (float*)(ws + 4096 + 32768);

    hipLaunchKernelGGL(k_prep, dim3(22), dim3(256), 0, stream, W1, W2, w6, w2q);
    hipLaunchKernelGGL(k_convs, dim3(B / 8), dim3(512), 0, stream, x, w6, b1, w2q, b2, h2);
    hipLaunchKernelGGL(k_fc, dim3(B / 16), dim3(256), 0, stream,
                       h2, L1, Lb1, L2, Lb2, L3, Lb3, out);
}

// Round 14
// 99.806 us; speedup vs baseline: 1.0614x; 1.0614x over previous
//
#include <hip/hip_runtime.h>
#include <math.h>

// LeNet-ish forward, fp32, B=8192.
// conv1+pool = stride-2 6x6 conv (w6 = W1 (*) ones(2,2), /4 at use).
// conv1 -> S1 (2x2 window-sum of sigmoid output) in LDS -> conv2 (S-trick)
// in the same kernel. h2 contiguous [B][320].
// r14: phase C was LDS-pipe-bound (5 of 7 ds_read_b128 per inner step were
// weights). Wave=cg remap + readfirstlane makes the weight address wave-
// uniform -> s_load from global w2q (L2-resident, constant cache); LDS
// traffic in phase C drops 71% and the w2s restage + barrier disappear.
//
// ws: [w6 4KB][w2q 32KB][h2: B*320 f32]

__device__ __forceinline__ float sigf(float v) {
    return 1.0f / (1.0f + __expf(-v));
}

// --- K0: prep. w6[ky][c][8] from W1; w2q repack. ---
__global__ void k_prep(const float* __restrict__ W1, const float* __restrict__ W2,
                       float* __restrict__ w6, float* __restrict__ w2q) {
    int i = blockIdx.x * 256 + threadIdx.x;
    if (i < 5000) {
        int kx = i % 5, t = i / 5;
        int ky = t % 5, t2 = t / 5;
        int ic = t2 % 10, c = t2 / 10;
        w2q[((ic * 5 + ky) * 20 + c) * 5 + kx] = W2[i];
    }
    int k = i - 5000;
    if (k >= 0 && k < 480) {
        int kx = k % 8, t = k / 8;
        int c = t % 10, ky = t / 10;
        float v = 0.f;
        if (kx < 6) {
            for (int dy = 0; dy < 2; ++dy)
                for (int dx = 0; dx < 2; ++dx) {
                    int sy = ky - dy, sx = kx - dx;
                    if (sy >= 0 && sy < 5 && sx >= 0 && sx < 5)
                        v += W1[c * 25 + sy * 5 + sx];
                }
        }
        w6[k] = v;
    }
}

// --- K1: fused convs. 512 thr, 8 img/block, 1024 blocks. ---
#define S1STR 1348  // 1348%32==4 -> image slabs bank-staggered

__global__ __launch_bounds__(512) void k_convs(
    const float* __restrict__ x, const float* __restrict__ w6g,
    const float* __restrict__ b1, const float* __restrict__ w2qg,
    const float* __restrict__ b2, float* __restrict__ h2) {
    __shared__ float S1t[8 * S1STR];   // 43136 B
    __shared__ float XR[6272];         // x tile [im8][784]
    __shared__ float wq1[480];         // [ky6][ch10][8]
    __shared__ float bs1[10];
    __shared__ float bs2[20];

    const int tid = threadIdx.x;
    const long img0 = (long)blockIdx.x * 8;

    {   // stage x tile (coalesced f4) + conv1 weights
        const float4* xg = (const float4*)(x + img0 * 784);
        float4* xl = (float4*)XR;
        for (int i = tid; i < 1568; i += 512) xl[i] = xg[i];
    }
    if (tid < 480) wq1[tid] = w6g[tid];
    else if (tid < 490) bs1[tid - 480] = b1[tid - 480];
    else if (tid < 510) bs2[tid - 490] = b2[tid - 490];
    __syncthreads();

    // ---- phase B: conv1(6x6 s2) + sigmoid + 2x2 window-sum -> S1t ----
    {
        const int im = tid >> 6, l = tid & 63;
        if (l < 60) {
            const int cc = l / 12, py = l % 12, ch0 = cc * 2;
            float acc0[12], acc1[12];
#pragma unroll
            for (int p = 0; p < 12; ++p) { acc0[p] = 0.f; acc1[p] = 0.f; }

            const float* xim = XR + im * 784;
#pragma unroll
            for (int ky = 0; ky < 6; ++ky) {
                const int r = 2 * py + ky;
                union { float4 v[7]; float f[28]; } R;
                const float4* rp = (const float4*)(xim + r * 28);
#pragma unroll
                for (int q = 0; q < 7; ++q) R.v[q] = rp[q];
                union { float4 v[2]; float f[8]; } W0, W1;
                const float* wb = &wq1[(ky * 10 + ch0) * 8];
                W0.v[0] = *(const float4*)(wb);
                W0.v[1] = *(const float4*)(wb + 4);
                W1.v[0] = *(const float4*)(wb + 8);
                W1.v[1] = *(const float4*)(wb + 12);
#pragma unroll
                for (int kx = 0; kx < 6; ++kx) {
                    const float w0 = W0.f[kx], w1 = W1.f[kx];
#pragma unroll
                    for (int px = 0; px < 12; ++px) {
                        const float xv = R.f[2 * px + kx];
                        acc0[px] += xv * w0;
                        acc1[px] += xv * w1;
                    }
                }
            }

#define FINISH_CH(ACC, CH)                                                   \
            {                                                                \
                float h[12];                                                 \
                _Pragma("unroll")                                            \
                for (int px = 0; px < 12; ++px)                              \
                    h[px] = sigf(ACC[px] * 0.25f + bs1[CH]);                 \
                float hh[11];                                                \
                _Pragma("unroll")                                            \
                for (int t = 0; t < 11; ++t) hh[t] = h[t] + h[t + 1];        \
                float o[12];                                                 \
                _Pragma("unroll")                                            \
                for (int t = 0; t < 11; ++t)                                 \
                    o[t] = hh[t] + __shfl_down(hh[t], 1, 64);                \
                o[11] = 0.f;                                                 \
                if (py < 11) {                                               \
                    float* sp = S1t + im * S1STR + (CH) * 132 + py * 12;     \
                    ((float4*)sp)[0] = make_float4(o[0], o[1], o[2], o[3]);  \
                    ((float4*)sp)[1] = make_float4(o[4], o[5], o[6], o[7]);  \
                    ((float4*)sp)[2] = make_float4(o[8], o[9], o[10], o[11]);\
                }                                                            \
            }
            FINISH_CH(acc0, ch0)
            FINISH_CH(acc1, ch0 + 1)
#undef FINISH_CH
        }
    }
    __syncthreads();

    // ---- phase C: conv2 + pool + sigmoid -> h2. ----
    // wave = cg (5 of 8 waves), lane = (im3,py2,xh1) -> 64/64 active.
    // Weights: wave-uniform address into global w2q -> scalar s_load path;
    // zero LDS instructions for W, FMA reads the weight from an SGPR.
    {
        const int w = tid >> 6, l = tid & 63;
        if (w < 5) {
            const int cg = __builtin_amdgcn_readfirstlane(w);
            const int im = l >> 3, py = (l >> 1) & 3, xh = l & 1;

            float acc[4][2];
#pragma unroll
            for (int a = 0; a < 4; ++a) { acc[a][0] = 0.f; acc[a][1] = 0.f; }

            const float* s1 = S1t + im * S1STR;
            const float* wg = w2qg + cg * 20;
            for (int ic = 0; ic < 10; ++ic) {
#pragma unroll
                for (int ky = 0; ky < 5; ++ky) {
                    const int ro = ic * 132 + (2 * py + ky) * 12 + xh * 4;
                    union { float4 v[2]; float f[8]; } R;
                    R.v[0] = *(const float4*)(s1 + ro);
                    R.v[1] = *(const float4*)(s1 + ro + 4);
                    const float* wrow = wg + (ic * 5 + ky) * 100;
#pragma unroll
                    for (int cc = 0; cc < 4; ++cc)
#pragma unroll
                        for (int kx = 0; kx < 5; ++kx) {
                            const float wv = wrow[cc * 5 + kx];  // s_load (uniform)
                            acc[cc][0] += R.f[kx] * wv;
                            acc[cc][1] += R.f[2 + kx] * wv;
                        }
                }
            }

            float* outp = h2 + (img0 + im) * 320 + (cg * 4) * 16 + py * 4 + xh * 2;
#pragma unroll
            for (int cc = 0; cc < 4; ++cc) {
                const float bv = bs2[cg * 4 + cc];
                float2 o;
                o.x = sigf(acc[cc][0] * 0.25f + bv);
                o.y = sigf(acc[cc][1] * 0.25f + bv);
                *(float2*)(outp + cc * 16) = o;
            }
        }
    }
}

// --- K2: FC chain, GEMM-style with LDS-resident weights (unchanged r13). ---
#define TSTR 18
__global__ __launch_bounds__(256) void k_fc(
    const float* __restrict__ h2, const float* __restrict__ L1,
    const float* __restrict__ Lb1, const float* __restrict__ L2,
    const float* __restrict__ Lb2, const float* __restrict__ L3,
    const float* __restrict__ Lb3, float* __restrict__ out) {
    __shared__ float arena[18480];   // 73920 B
    float* h2t = arena;              // [320][18]  = 5760   (FC1)
    float* wt  = arena + 5760;       // [2][32][128] = 8192 (FC1)
    float* g1t = arena + 13952;      // [120][18] = 2160
    float* g2t = arena + 16112;      // [84][18]  = 1512
    float* L3s = arena + 17624;      // 840 + 10
    // FC2 phase: w2 = arena[0..10560) [120][88] (overlaps h2t+wt, both dead)

    const int tid = threadIdx.x;
    const long img0 = (long)blockIdx.x * 16;

    for (int i = tid; i < 1280; i += 256) {
        const int im = i / 80, fq = i % 80;
        float4 v = *(const float4*)(h2 + (img0 + im) * 320 + fq * 4);
        h2t[(fq * 4 + 0) * TSTR + im] = v.x;
        h2t[(fq * 4 + 1) * TSTR + im] = v.y;
        h2t[(fq * 4 + 2) * TSTR + im] = v.z;
        h2t[(fq * 4 + 3) * TSTR + im] = v.w;
    }
#pragma unroll
    for (int r = 0; r < 4; ++r) {
        const int idx = tid + 256 * r, row = idx >> 5, c4 = idx & 31;
        if (c4 < 30)
            *(float4*)(wt + row * 128 + c4 * 4) =
                *(const float4*)(L1 + row * 120 + c4 * 4);
    }
    __syncthreads();

    const int p = tid >> 5, jg = tid & 31;
    const int jc = jg < 30 ? jg : 29;

    // ---- FC1: 320 -> 120, 10 K-tiles of 32, double-buffered ----
    float acc[4][2];
    {
        union { float4 v; float f[4]; } bv;
        bv.v = *(const float4*)(Lb1 + jc * 4);
#pragma unroll
        for (int q = 0; q < 4; ++q) { acc[q][0] = bv.f[q]; acc[q][1] = bv.f[q]; }
    }
    int cur = 0;
    for (int t = 0; t < 10; ++t) {
        float4 wr0, wr1, wr2, wr3;
        if (t < 9) {
            const int k0n = (t + 1) * 32;
            const int r0 = tid >> 5, c0 = tid & 31;
            wr0 = (c0 < 30) ? *(const float4*)(L1 + (k0n + r0) * 120 + c0 * 4) : make_float4(0, 0, 0, 0);
            wr1 = (c0 < 30) ? *(const float4*)(L1 + (k0n + ((tid + 256) >> 5)) * 120 + c0 * 4) : make_float4(0, 0, 0, 0);
            wr2 = (c0 < 30) ? *(const float4*)(L1 + (k0n + ((tid + 512) >> 5)) * 120 + c0 * 4) : make_float4(0, 0, 0, 0);
            wr3 = (c0 < 30) ? *(const float4*)(L1 + (k0n + ((tid + 768) >> 5)) * 120 + c0 * 4) : make_float4(0, 0, 0, 0);
        }
        const float* wb = wt + cur * 4096;
        const int kb = t * 32;
#pragma unroll
        for (int k = 0; k < 32; ++k) {
            union { float4 v; float f[4]; } w;
            w.v = *(const float4*)(wb + k * 128 + jc * 4);
            const float2 h = *(const float2*)&h2t[(kb + k) * TSTR + p * 2];
#pragma unroll
            for (int q = 0; q < 4; ++q) {
                acc[q][0] += w.f[q] * h.x;
                acc[q][1] += w.f[q] * h.y;
            }
        }
        if (t < 9) {
            float* wd = wt + (cur ^ 1) * 4096;
            const int c0 = tid & 31;
            if (c0 < 30) {
                *(float4*)(wd + (tid >> 5) * 128 + c0 * 4) = wr0;
                *(float4*)(wd + ((tid + 256) >> 5) * 128 + c0 * 4) = wr1;
                *(float4*)(wd + ((tid + 512) >> 5) * 128 + c0 * 4) = wr2;
                *(float4*)(wd + ((tid + 768) >> 5) * 128 + c0 * 4) = wr3;
            }
            cur ^= 1;
        }
        __syncthreads();
    }
    if (jg < 30) {
#pragma unroll
        for (int q = 0; q < 4; ++q) {
            g1t[(jg * 4 + q) * TSTR + p * 2 + 0] = sigf(acc[q][0]);
            g1t[(jg * 4 + q) * TSTR + p * 2 + 1] = sigf(acc[q][1]);
        }
    }
    __syncthreads();

    // ---- stage FC2 weights [120][88] + L3/Lb3 ----
    for (int i = tid; i < 2520; i += 256) {
        const int row = i / 21, c4 = i % 21;
        *(float4*)(arena + row * 88 + c4 * 4) =
            *(const float4*)(L2 + row * 84 + c4 * 4);
    }
    for (int i = tid; i < 840; i += 256) L3s[i] = L3[i];
    if (tid < 10) L3s[840 + tid] = Lb3[tid];
    __syncthreads();

    // ---- FC2: 120 -> 84 ----
    if (jg < 21) {
        union { float4 v; float f[4]; } bv;
        bv.v = *(const float4*)(Lb2 + jg * 4);
        float a2[4][2];
#pragma unroll
        for (int q = 0; q < 4; ++q) { a2[q][0] = bv.f[q]; a2[q][1] = bv.f[q]; }
#pragma unroll 4
        for (int k = 0; k < 120; ++k) {
            union { float4 v; float f[4]; } w;
            w.v = *(const float4*)(arena + k * 88 + jg * 4);
            const float2 h = *(const float2*)&g1t[k * TSTR + p * 2];
#pragma unroll
            for (int q = 0; q < 4; ++q) {
                a2[q][0] += w.f[q] * h.x;
                a2[q][1] += w.f[q] * h.y;
            }
        }
#pragma unroll
        for (int q = 0; q < 4; ++q) {
            g2t[(jg * 4 + q) * TSTR + p * 2 + 0] = sigf(a2[q][0]);
            g2t[(jg * 4 + q) * TSTR + p * 2 + 1] = sigf(a2[q][1]);
        }
    }
    __syncthreads();

    // ---- FC3: 84 -> 10 ----
    if (tid < 160) {
        const int im = tid / 10, j = tid % 10;
        float a = L3s[840 + j];
#pragma unroll 4
        for (int i = 0; i < 84; ++i)
            a += g2t[i * TSTR + im] * L3s[i * 10 + j];
        out[(img0 + im) * 10 + j] = a;
    }
}

extern "C" void kernel_launch(void* const* d_in, const int* in_sizes, int n_in,
                              void* d_out, int out_size, void* d_ws, size_t ws_size,
                              hipStream_t stream) {
    const float* x   = (const float*)d_in[0];
    const float* W1  = (const float*)d_in[1];
    const float* b1  = (const float*)d_in[2];
    const float* W2  = (const float*)d_in[3];
    const float* b2  = (const float*)d_in[4];
    const float* L1  = (const float*)d_in[5];
    const float* Lb1 = (const float*)d_in[6];
    const float* L2  = (const float*)d_in[7];
    const float* Lb2 = (const float*)d_in[8];
    const float* L3  = (const float*)d_in[9];
    const float* Lb3 = (const float*)d_in[10];
    float* out = (float*)d_out;

    const int B = in_sizes[0] / 784;  // 8192

    char* ws = (char*)d_ws;
    float* w6  = (float*)ws;                 // 1.9KB (pad 4KB)
    float* w2q = (float*)(ws + 4096);        // 20KB (pad 32KB)
    float* h2  = (float*)(ws + 4096 + 32768);

    hipLaunchKernelGGL(k_prep, dim3(22), dim3(256), 0, stream, W1, W2, w6, w2q);
    hipLaunchKernelGGL(k_convs, dim3(B / 8), dim3(512), 0, stream, x, w6, b1, w2q, b2, h2);
    hipLaunchKernelGGL(k_fc, dim3(B / 16), dim3(256), 0, stream,
                       h2, L1, Lb1, L2, Lb2, L3, Lb3, out);
}